// Round 8
// baseline (382.885 us; speedup 1.0000x reference)
//
#include <hip/hip_runtime.h>
#include <hip/hip_bf16.h>

typedef __bf16 bf16_t;
typedef __bf16 bf16x8 __attribute__((ext_vector_type(8)));
typedef __bf16 bf16x4 __attribute__((ext_vector_type(4)));
typedef float  f32x4  __attribute__((ext_vector_type(4)));
typedef int    i32x4  __attribute__((ext_vector_type(4)));

#define MFMA16(a,b,c) __builtin_amdgcn_mfma_f32_16x16x32_bf16((a),(b),(c),0,0,0)

static constexpr int Bn = 4, Hn = 16, Dh = 64, SEQ = 1024;

__device__ __forceinline__ void gll16(const void* g, void* l) {
    __builtin_amdgcn_global_load_lds(
        (const __attribute__((address_space(1))) void*)g,
        (__attribute__((address_space(3))) void*)l, 16, 0, 0);
}

// ---------------------------------------------------------------------------
// Transpose-convert all 4 weight matrices f32 [R][C] -> bf16 [C][R].
// ---------------------------------------------------------------------------
__global__ __launch_bounds__(256)
void wtrans_kernel(const float* __restrict__ s0, const float* __restrict__ s1,
                   const float* __restrict__ s2, const float* __restrict__ s3,
                   bf16_t* __restrict__ d0, bf16_t* __restrict__ d1,
                   bf16_t* __restrict__ d2, bf16_t* __restrict__ d3)
{
    __shared__ bf16_t tile[64][72];
    const int bid = blockIdx.x, t = threadIdx.x;
    const float* src; bf16_t* dst; int R, C, tr, tc;
    if (bid < 256)      { src = s0; dst = d0; R = 1024; C = 1024; tr = bid >> 4;        tc = bid & 15; }
    else if (bid < 512) { src = s1; dst = d1; R = 1024; C = 1024; tr = (bid-256) >> 4;  tc = (bid-256) & 15; }
    else if (bid < 704) { src = s2; dst = d2; R = 768;  C = 1024; tr = (bid-512) >> 4;  tc = (bid-512) & 15; }
    else                { src = s3; dst = d3; R = 1024; C = 768;  tr = (bid-704) / 12;  tc = (bid-704) % 12; }
    const int r0 = tr * 64, c0 = tc * 64;
    const int lr = t >> 2, lc0 = (t & 3) * 16;
    #pragma unroll
    for (int i = 0; i < 4; i++) {
        f32x4 v = *(const f32x4*)&src[(size_t)(r0 + lr) * C + c0 + lc0 + i * 4];
        #pragma unroll
        for (int j = 0; j < 4; j++) tile[lr][lc0 + i * 4 + j] = (bf16_t)v[j];
    }
    __syncthreads();
    const int oc = t >> 2, orc0 = (t & 3) * 16;
    #pragma unroll
    for (int i = 0; i < 2; i++) {
        bf16x8 vv;
        #pragma unroll
        for (int j = 0; j < 8; j++) vv[j] = tile[orc0 + i * 8 + j][oc];
        *(bf16x8*)&dst[(size_t)(c0 + oc) * R + r0 + orc0 + i * 8] = vv;
    }
}

// ---------------------------------------------------------------------------
// GEMM: C[M][N] = A[M][KD] @ Bt^T + bias. Tile 128x64, BK=64, dbuf LDS,
// one barrier per K-step. LDS tiles XOR-swizzled (byte ^= (row&7)<<4):
// gll16 path pre-swizzles the GLOBAL source per-lane (dest stays linear),
// f32-A reg path writes to swizzled offsets; all ds_read_b128 use the same
// XOR -> conflict-free (was 8-way at 64B row stride).
//   MODE 0: bf16 out [B][H][S][64]; MODE 1: bf16 out [B][H][64][S];
//   MODE 2: f32 out [M][N].  Grid: dim3(N/64, M/128).
// ---------------------------------------------------------------------------
template<int KD, int N, int MODE, typename AT>
__global__ __launch_bounds__(256)
void gemm_bt(const AT* __restrict__ A, const bf16_t* __restrict__ Bt,
             const float* __restrict__ bias, void* __restrict__ outp,
             float scale)
{
    __shared__ bf16_t As[2][128 * 64];   // 16 KB each, 128B rows, swizzled
    __shared__ bf16_t Bs[2][64 * 64];    //  8 KB each
    __shared__ bf16_t Ct[(MODE == 2) ? 1 : 128 * 72];
    const int t = threadIdx.x, lane = t & 63, w = t >> 6;
    const int wr = w >> 1, wc = w & 1;
    const int row0 = blockIdx.y * 128, col0 = blockIdx.x * 64;
    const int lrow = lane & 15, lk4 = lane >> 4, lk8 = lk4 * 8;
    const int ar = t >> 1, ac0 = (t & 1) * 32;    // f32-A staging: 32 elems/thr

    f32x4 acc[4][2] = {};
    f32x4 a_f[8];

    auto aload = [&](int kk) {
        if constexpr (sizeof(AT) == 4) {
            const float* src = (const float*)A + (size_t)(row0 + ar) * KD + kk + ac0;
            #pragma unroll
            for (int j = 0; j < 8; j++) a_f[j] = *(const f32x4*)(src + j * 4);
        }
    };
    auto awrite = [&](int buf) {
        if constexpr (sizeof(AT) == 4) {
            char* base = (char*)&As[buf][0] + ar * 128;
            const int aswz = (ar & 7) << 4;
            #pragma unroll
            for (int j = 0; j < 4; j++) {
                bf16x8 v;
                #pragma unroll
                for (int e = 0; e < 4; e++) {
                    v[e]     = (bf16_t)a_f[2 * j][e];
                    v[4 + e] = (bf16_t)a_f[2 * j + 1][e];
                }
                *(bf16x8*)(base + ((ac0 * 2 + j * 16) ^ aswz)) = v;
            }
        }
    };
    auto astage_gll = [&](int buf, int kk) {   // bf16 A (MODE 2), pre-swz src
        if constexpr (sizeof(AT) == 2) {
            #pragma unroll
            for (int j = 0; j < 4; j++) {
                const int idx = j * 256 + t;
                const int row = idx >> 3, colb = (idx & 7) * 16;
                const bf16_t* g = (const bf16_t*)A + (size_t)(row0 + row) * KD +
                                  kk + ((colb ^ ((row & 7) << 4)) >> 1);
                gll16(g, (char*)&As[buf][0] + (j * 256 + w * 64) * 16);
            }
        }
    };
    auto bstage = [&](int buf, int kk) {       // pre-swizzled source
        #pragma unroll
        for (int j = 0; j < 2; j++) {
            const int idx = j * 256 + t;
            const int n = idx >> 3, colb = (idx & 7) * 16;
            const bf16_t* g = Bt + (size_t)(col0 + n) * KD +
                              kk + ((colb ^ ((n & 7) << 4)) >> 1);
            gll16(g, (char*)&Bs[buf][0] + (j * 256 + w * 64) * 16);
        }
    };

    constexpr int NB = KD / 64;
    if constexpr (sizeof(AT) == 4) { aload(0); awrite(0); }
    else                            astage_gll(0, 0);
    bstage(0, 0);

    const char* AsC0 = (const char*)&As[0][0];
    const char* BsC0 = (const char*)&Bs[0][0];
    for (int s = 0; s < NB; s++) {
        __syncthreads();                 // buf[s&1] ready (vmcnt+lgkm drain)
        const int cur = s & 1;
        if (s + 1 < NB) {
            bstage(cur ^ 1, (s + 1) * 64);
            if constexpr (sizeof(AT) == 4) aload((s + 1) * 64);
            else                           astage_gll(cur ^ 1, (s + 1) * 64);
        }
        const char* AsC = AsC0 + cur * (128 * 128);
        const char* BsC = BsC0 + cur * (64 * 128);
        #pragma unroll
        for (int h = 0; h < 2; h++) {
            bf16x8 af[4], bfr[2];
            #pragma unroll
            for (int mf = 0; mf < 4; mf++) {
                const int R = wr * 64 + mf * 16 + lrow;
                af[mf] = *(const bf16x8*)(AsC + R * 128 +
                          (((h * 32 + lk8) * 2) ^ ((R & 7) << 4)));
            }
            #pragma unroll
            for (int nf = 0; nf < 2; nf++) {
                const int Rn = wc * 32 + nf * 16 + lrow;
                bfr[nf] = *(const bf16x8*)(BsC + Rn * 128 +
                          (((h * 32 + lk8) * 2) ^ ((Rn & 7) << 4)));
            }
            #pragma unroll
            for (int mf = 0; mf < 4; mf++)
                #pragma unroll
                for (int nf = 0; nf < 2; nf++)
                    acc[mf][nf] = MFMA16(af[mf], bfr[nf], acc[mf][nf]);
        }
        if (s + 1 < NB) { if constexpr (sizeof(AT) == 4) awrite(cur ^ 1); }
    }

    if constexpr (MODE == 2) {
        #pragma unroll
        for (int mf = 0; mf < 4; mf++)
            #pragma unroll
            for (int nf = 0; nf < 2; nf++) {
                const int gcol = col0 + wc * 32 + nf * 16 + lrow;
                const float bv = bias[gcol];
                #pragma unroll
                for (int r = 0; r < 4; r++) {
                    const int grow = row0 + wr * 64 + mf * 16 + lk4 * 4 + r;
                    ((float*)outp)[(size_t)grow * N + gcol] = (acc[mf][nf][r] + bv) * scale;
                }
            }
    } else {
        __syncthreads();
        #pragma unroll
        for (int mf = 0; mf < 4; mf++)
            #pragma unroll
            for (int nf = 0; nf < 2; nf++) {
                const int lcol = wc * 32 + nf * 16 + lrow;
                const float bv = bias[col0 + lcol];
                #pragma unroll
                for (int r = 0; r < 4; r++)
                    Ct[(wr * 64 + mf * 16 + lk4 * 4 + r) * 72 + lcol] =
                        (bf16_t)((acc[mf][nf][r] + bv) * scale);
            }
        __syncthreads();
        const int h = col0 >> 6, b = row0 >> 10;
        bf16_t* op = (bf16_t*)outp + ((size_t)(b * Hn + h) << 16);  // *1024*64
        if constexpr (MODE == 0) {
            #pragma unroll
            for (int j = 0; j < 4; j++) {
                const int sl = j * 32 + (t >> 3), cl0 = (t & 7) * 8;
                bf16x8 v = *(const bf16x8*)&Ct[sl * 72 + cl0];
                *(bf16x8*)&op[(size_t)((row0 & 1023) + sl) * 64 + cl0] = v;
            }
        } else {
            #pragma unroll
            for (int jj = 0; jj < 2; jj++) {
                const int cl = jj * 32 + (t >> 3);
                #pragma unroll
                for (int k = 0; k < 2; k++) {
                    const int sl0 = k * 64 + (t & 7) * 8;
                    bf16x8 v;
                    #pragma unroll
                    for (int i = 0; i < 8; i++) v[i] = Ct[(sl0 + i) * 72 + cl];
                    *(bf16x8*)&op[(size_t)cl * 1024 + (row0 & 1023) + sl0] = v;
                }
            }
        }
    }
}

// ---------------------------------------------------------------------------
// Flash attention, swapped operands, no barriers. This round:
//  - l computed by PV MFMA via all-ones A row (kills 16 serial adds + 2 shfl)
//  - defer-max (THR=8): skip max-shfls and O-rescale when no lane's tile max
//    exceeds m_run+8 (exact for masked rows: P=1, l=1024 -> uniform)
//  - depth-4 tree max; s_setprio around MFMA clusters
// ---------------------------------------------------------------------------
__global__ __launch_bounds__(256)
void attn_kernel(const bf16_t* __restrict__ kbuf, const bf16_t* __restrict__ vT,
                 const bf16_t* __restrict__ qbuf, const int* __restrict__ qmask,
                 const int* __restrict__ kmask, bf16_t* __restrict__ ctx)
{
    __shared__ bf16_t Pall[4][16 * 64];
    const int t = threadIdx.x, lane = t & 63, w = t >> 6;
    const int bidx = blockIdx.x;
    const int qt = bidx & 15, bh = bidx >> 4, b = bh >> 4, h = bh & 15;
    const int lrow = lane & 15, lk4 = lane >> 4, lk8 = lk4 * 8;
    const int wrow0 = qt * 64 + w * 16;
    const bf16_t* kb = kbuf + (size_t)bh * SEQ * Dh;
    const bf16_t* vb = vT + (size_t)bh * Dh * SEQ;
    char* Pw = (char*)&Pall[w][0];
    const int sw = (lrow & 7) << 4;

    bf16x8 aq0, aq1;
    {
        const bf16_t* qp = qbuf + ((size_t)bh * SEQ + wrow0 + lrow) * Dh + lk8;
        aq0 = *(const bf16x8*)(qp);
        aq1 = *(const bf16x8*)(qp + 32);
    }
    const int qm = qmask[b * SEQ + wrow0 + lrow];

    bf16x8 ones;
    #pragma unroll
    for (int i = 0; i < 8; i++) ones[i] = (bf16_t)1.0f;

    float m_run = -__builtin_inff();
    f32x4 o[4] = {};
    f32x4 o_l  = {};     // row-sum accumulator via ones-MFMA

    bf16x8 kc0[4], kc1[4];
    #pragma unroll
    for (int nf = 0; nf < 4; nf++) {
        const bf16_t* kp = kb + (size_t)(nf * 16 + lrow) * Dh + lk8;
        kc0[nf] = *(const bf16x8*)(kp);
        kc1[nf] = *(const bf16x8*)(kp + 32);
    }

    for (int kt = 0; kt < 16; kt++) {
        const int key0 = kt * 64;
        bf16x8 vf0[4], vf1[4];
        #pragma unroll
        for (int nf = 0; nf < 4; nf++) {
            const bf16_t* vp = vb + (size_t)(nf * 16 + lrow) * SEQ + key0 + lk8;
            vf0[nf] = *(const bf16x8*)(vp);
            vf1[nf] = *(const bf16x8*)(vp + 32);
        }
        i32x4 km[4];
        #pragma unroll
        for (int nf = 0; nf < 4; nf++)
            km[nf] = *(const i32x4*)&kmask[b * SEQ + key0 + nf * 16 + lk4 * 4];
        f32x4 s4[4] = {};
        __builtin_amdgcn_s_setprio(1);
        #pragma unroll
        for (int nf = 0; nf < 4; nf++) {
            s4[nf] = MFMA16(kc0[nf], aq0, s4[nf]);
            s4[nf] = MFMA16(kc1[nf], aq1, s4[nf]);
        }
        __builtin_amdgcn_s_setprio(0);
        bf16x8 kn0[4], kn1[4];
        if (kt < 15) {
            #pragma unroll
            for (int nf = 0; nf < 4; nf++) {
                const bf16_t* kp = kb + (size_t)(key0 + 64 + nf * 16 + lrow) * Dh + lk8;
                kn0[nf] = *(const bf16x8*)(kp);
                kn1[nf] = *(const bf16x8*)(kp + 32);
            }
        }
        // mask select (exact -1e18) + tree max
        float p[4][4], mx[4];
        #pragma unroll
        for (int nf = 0; nf < 4; nf++) {
            #pragma unroll
            for (int r = 0; r < 4; r++)
                p[nf][r] = (qm && km[nf][r]) ? s4[nf][r] : -1e18f;
            mx[nf] = fmaxf(fmaxf(p[nf][0], p[nf][1]), fmaxf(p[nf][2], p[nf][3]));
        }
        const float pmax = fmaxf(fmaxf(mx[0], mx[1]), fmaxf(mx[2], mx[3]));
        // defer-max: full path only when a lane's max beats m_run by > 8
        if (!__all(pmax - m_run <= 8.0f)) {
            float mt = fmaxf(pmax, __shfl_xor(pmax, 16));
            mt = fmaxf(mt, __shfl_xor(mt, 32));
            const float resc = __expf(m_run - mt);
            m_run = mt;
            #pragma unroll
            for (int nf = 0; nf < 4; nf++)
                #pragma unroll
                for (int r = 0; r < 4; r++) o[nf][r] *= resc;
            #pragma unroll
            for (int r = 0; r < 4; r++) o_l[r] *= resc;
        }
        #pragma unroll
        for (int nf = 0; nf < 4; nf++)
            #pragma unroll
            for (int r = 0; r < 4; r++) p[nf][r] = __expf(p[nf][r] - m_run);
        // P -> LDS (per-wave strip, swizzled, no barrier)
        #pragma unroll
        for (int nf = 0; nf < 4; nf++) {
            bf16x4 pk;
            #pragma unroll
            for (int r = 0; r < 4; r++) pk[r] = (bf16_t)p[nf][r];
            *(bf16x4*)(Pw + lrow * 128 + ((nf * 32 + lk4 * 8) ^ sw)) = pk;
        }
        bf16x8 pa0 = *(const bf16x8*)(Pw + lrow * 128 + ((lk4 * 16) ^ sw));
        bf16x8 pa1 = *(const bf16x8*)(Pw + lrow * 128 + ((64 + lk4 * 16) ^ sw));
        __builtin_amdgcn_s_setprio(1);
        #pragma unroll
        for (int nf = 0; nf < 4; nf++) {
            o[nf] = MFMA16(vf0[nf], pa0, o[nf]);
            o[nf] = MFMA16(vf1[nf], pa1, o[nf]);
        }
        o_l = MFMA16(ones, pa0, o_l);      // l += sum_k P[k][q]
        o_l = MFMA16(ones, pa1, o_l);
        __builtin_amdgcn_s_setprio(0);
        #pragma unroll
        for (int nf = 0; nf < 4; nf++) { kc0[nf] = kn0[nf]; kc1[nf] = kn1[nf]; }
    }
    // finalize: O/l -> strip [q][d] -> coalesced ctx stores
    const float inv = 1.0f / o_l[0];
    #pragma unroll
    for (int nf = 0; nf < 4; nf++) {
        bf16x4 pk;
        #pragma unroll
        for (int r = 0; r < 4; r++) pk[r] = (bf16_t)(o[nf][r] * inv);
        *(bf16x4*)(Pw + lrow * 128 + ((nf * 32 + lk4 * 8) ^ sw)) = pk;
    }
    const int qp2 = lane >> 2, ch = lane & 3;
    const int sw2 = (qp2 & 7) << 4;
    bf16x8 o0 = *(const bf16x8*)(Pw + qp2 * 128 + ((ch * 32) ^ sw2));
    bf16x8 o1 = *(const bf16x8*)(Pw + qp2 * 128 + ((ch * 32 + 16) ^ sw2));
    bf16_t* cp = ctx + ((size_t)(b * SEQ + wrow0 + qp2)) * 1024 + h * 64 + ch * 16;
    *(bf16x8*)cp = o0;
    *(bf16x8*)(cp + 8) = o1;
}

// ---------------------------------------------------------------------------
// top_score = pre-mask scores of head 0 (coalesced f32 stores).
// ---------------------------------------------------------------------------
__global__ __launch_bounds__(256)
void topsc_kernel(const bf16_t* __restrict__ kbuf, const bf16_t* __restrict__ qbuf,
                  float* __restrict__ topsc)
{
    const int t = threadIdx.x, lane = t & 63, w = t >> 6;
    const int bx = blockIdx.x;
    const int b = bx >> 6, qt = (bx >> 2) & 15, kq = bx & 3;
    const int lrow = lane & 15, lk4 = lane >> 4, lk8 = lk4 * 8;
    const int wrow0 = qt * 64 + w * 16;
    const bf16_t* kb = kbuf + ((size_t)(b * Hn)) * SEQ * Dh;   // head 0
    const bf16_t* qp = qbuf + ((size_t)(b * Hn)) * SEQ * Dh
                     + (size_t)(wrow0 + lrow) * Dh + lk8;
    bf16x8 aq0 = *(const bf16x8*)(qp);
    bf16x8 aq1 = *(const bf16x8*)(qp + 32);
    for (int kt = 0; kt < 4; kt++) {
        const int key0 = kq * 256 + kt * 64;
        f32x4 s4[4] = {};
        #pragma unroll
        for (int nf = 0; nf < 4; nf++) {
            const bf16_t* kp = kb + (size_t)(key0 + nf * 16 + lrow) * Dh + lk8;
            s4[nf] = MFMA16(aq0, *(const bf16x8*)(kp), s4[nf]);
            s4[nf] = MFMA16(aq1, *(const bf16x8*)(kp + 32), s4[nf]);
        }
        #pragma unroll
        for (int nf = 0; nf < 4; nf++)
            #pragma unroll
            for (int r = 0; r < 4; r++)
                topsc[(size_t)(b * SEQ + wrow0 + lk4 * 4 + r) * SEQ +
                      key0 + nf * 16 + lrow] = s4[nf][r];
    }
}

// ---------------------------------------------------------------------------
extern "C" void kernel_launch(void* const* d_in, const int* in_sizes, int n_in,
                              void* d_out, int out_size, void* d_ws, size_t ws_size,
                              hipStream_t stream)
{
    const float* key   = (const float*)d_in[0];
    const float* value = (const float*)d_in[1];
    const float* query = (const float*)d_in[2];
    const int*   mask  = (const int*)d_in[3];
    const int*   amask = (const int*)d_in[4];
    const float* Wk = (const float*)d_in[5];
    const float* bk = (const float*)d_in[6];
    const float* Wv = (const float*)d_in[7];
    const float* bv = (const float*)d_in[8];
    const float* Wq = (const float*)d_in[9];
    const float* bq = (const float*)d_in[10];
    const float* Wo = (const float*)d_in[11];
    const float* bo = (const float*)d_in[12];

    const size_t per = (size_t)Bn * Hn * SEQ * Dh;          // 4M elems
    bf16_t* kproj = (bf16_t*)d_ws;
    bf16_t* vT    = kproj + per;
    bf16_t* qproj = vT + per;
    bf16_t* ctx   = qproj + per;

    float* outf = (float*)d_out;
    bf16_t* WkT = (bf16_t*)(outf + (size_t)Bn * SEQ * 768);
    bf16_t* WvT = WkT + 1024 * 1024;
    bf16_t* WqT = WvT + 1024 * 1024;    // [1024][768]
    bf16_t* WoT = WqT + 1024 * 768;     // [768][1024]
    float* topsc = outf + (size_t)Bn * SEQ * 768;

    wtrans_kernel<<<896, 256, 0, stream>>>(Wk, Wv, Wq, Wo, WkT, WvT, WqT, WoT);
    gemm_bt<1024, 1024, 0, float><<<dim3(16, 32), 256, 0, stream>>>(key,   WkT, bk, kproj, 1.0f);
    gemm_bt<1024, 1024, 1, float><<<dim3(16, 32), 256, 0, stream>>>(value, WvT, bv, vT,    1.0f);
    gemm_bt< 768, 1024, 0, float><<<dim3(16, 32), 256, 0, stream>>>(query, WqT, bq, qproj, 0.125f);
    attn_kernel<<<dim3(Bn * Hn * 16), 256, 0, stream>>>(kproj, vT, qproj, mask, amask, ctx);
    gemm_bt<1024, 768, 2, bf16_t><<<dim3(12, 32), 256, 0, stream>>>(ctx, WoT, bo, outf, 1.0f);
    topsc_kernel<<<256, 256, 0, stream>>>(kproj, qproj, topsc);
}

// Round 14
// 339.732 us; speedup vs baseline: 1.1270x; 1.1270x over previous
//
#include <hip/hip_runtime.h>
#include <hip/hip_bf16.h>

typedef __bf16 bf16_t;
typedef __bf16 bf16x8 __attribute__((ext_vector_type(8)));
typedef __bf16 bf16x4 __attribute__((ext_vector_type(4)));
typedef float  f32x4  __attribute__((ext_vector_type(4)));
typedef int    i32x4  __attribute__((ext_vector_type(4)));

#define MFMA16(a,b,c) __builtin_amdgcn_mfma_f32_16x16x32_bf16((a),(b),(c),0,0,0)

static constexpr int Bn = 4, Hn = 16, Dh = 64, SEQ = 1024;

__device__ __forceinline__ void gll16(const void* g, void* l) {
    __builtin_amdgcn_global_load_lds(
        (const __attribute__((address_space(1))) void*)g,
        (__attribute__((address_space(3))) void*)l, 16, 0, 0);
}

// ---------------------------------------------------------------------------
// Transpose-convert all 4 weight matrices f32 [R][C] -> bf16 [C][R].
// ---------------------------------------------------------------------------
__global__ __launch_bounds__(256)
void wtrans_kernel(const float* __restrict__ s0, const float* __restrict__ s1,
                   const float* __restrict__ s2, const float* __restrict__ s3,
                   bf16_t* __restrict__ d0, bf16_t* __restrict__ d1,
                   bf16_t* __restrict__ d2, bf16_t* __restrict__ d3)
{
    __shared__ bf16_t tile[64][68];   // 136B stride: bank step 2 -> conflict-light
    const int bid = blockIdx.x, t = threadIdx.x;
    const float* src; bf16_t* dst; int R, C, tr, tc;
    if (bid < 256)      { src = s0; dst = d0; R = 1024; C = 1024; tr = bid >> 4;        tc = bid & 15; }
    else if (bid < 512) { src = s1; dst = d1; R = 1024; C = 1024; tr = (bid-256) >> 4;  tc = (bid-256) & 15; }
    else if (bid < 704) { src = s2; dst = d2; R = 768;  C = 1024; tr = (bid-512) >> 4;  tc = (bid-512) & 15; }
    else                { src = s3; dst = d3; R = 1024; C = 768;  tr = (bid-704) / 12;  tc = (bid-704) % 12; }
    const int r0 = tr * 64, c0 = tc * 64;
    const int lr = t >> 2, lc0 = (t & 3) * 16;
    #pragma unroll
    for (int i = 0; i < 4; i++) {
        f32x4 v = *(const f32x4*)&src[(size_t)(r0 + lr) * C + c0 + lc0 + i * 4];
        #pragma unroll
        for (int j = 0; j < 4; j++) tile[lr][lc0 + i * 4 + j] = (bf16_t)v[j];
    }
    __syncthreads();
    const int oc = t >> 2, orc0 = (t & 3) * 16;
    #pragma unroll
    for (int i = 0; i < 2; i++) {
        bf16x8 vv;
        #pragma unroll
        for (int j = 0; j < 8; j++) vv[j] = tile[orc0 + i * 8 + j][oc];
        *(bf16x8*)&dst[(size_t)(c0 + oc) * R + r0 + orc0 + i * 8] = vv;
    }
}

// ---------------------------------------------------------------------------
// GEMM: C[M][N] = A[M][KD] @ Bt^T + bias. Tile 64x64, BK=64, dbuf LDS,
// 1 barrier/K-step, XOR-swizzled LDS (byte ^= (row&7)<<4) with pre-swizzled
// gll16 sources. 1D grid, XCD-locality decode: each XCD owns 8 row-panels.
// 32KB LDS -> 4 blocks/CU (16 waves/CU).  Ct (epilogue bounce) aliases As.
//   MODE 0: bf16 out [B][H][S][64]; MODE 1: bf16 out [B][H][64][S];
//   MODE 2: f32 out [M][N].  Grid: GX*(M/64) blocks, M=4096.
// ---------------------------------------------------------------------------
template<int KD, int N, int MODE, int GX, typename AT>
__global__ __launch_bounds__(256)
void gemm_bt(const AT* __restrict__ A, const bf16_t* __restrict__ Bt,
             const float* __restrict__ bias, void* __restrict__ outp,
             float scale)
{
    __shared__ bf16_t As[2][64 * 64];    // 8 KB each, 128B rows, swizzled
    __shared__ bf16_t Bs[2][64 * 64];
    bf16_t* Ct = &As[0][0];              // aliased: used only after K-loop
    const int t = threadIdx.x, lane = t & 63, w = t >> 6;
    const int wr = w >> 1, wc = w & 1;
    const int bidx = blockIdx.x;
    const int xcd = bidx & 7, slot = bidx >> 3;
    const int row0 = (xcd + 8 * (slot / GX)) * 64;
    const int col0 = (slot % GX) * 64;
    const int lrow = lane & 15, lk4 = lane >> 4, lk8 = lk4 * 8;
    const int ar = t >> 2, ac0 = (t & 3) * 16;    // f32-A staging: 16 f32/thr

    f32x4 acc[2][2] = {};
    f32x4 a_f[4];

    auto aload = [&](int kk) {
        if constexpr (sizeof(AT) == 4) {
            const float* src = (const float*)A + (size_t)(row0 + ar) * KD + kk + ac0;
            #pragma unroll
            for (int j = 0; j < 4; j++) a_f[j] = *(const f32x4*)(src + j * 4);
        }
    };
    auto awrite = [&](int buf) {
        if constexpr (sizeof(AT) == 4) {
            char* base = (char*)&As[buf][0] + ar * 128;
            const int aswz = (ar & 7) << 4;
            #pragma unroll
            for (int j = 0; j < 2; j++) {
                bf16x8 v;
                #pragma unroll
                for (int e = 0; e < 4; e++) {
                    v[e]     = (bf16_t)a_f[2 * j][e];
                    v[4 + e] = (bf16_t)a_f[2 * j + 1][e];
                }
                *(bf16x8*)(base + ((ac0 * 2 + j * 16) ^ aswz)) = v;
            }
        }
    };
    auto astage_gll = [&](int buf, int kk) {   // bf16 A (MODE 2), pre-swz src
        if constexpr (sizeof(AT) == 2) {
            #pragma unroll
            for (int j = 0; j < 2; j++) {
                const int idx = j * 256 + t;
                const int row = idx >> 3, colb = (idx & 7) * 16;
                const bf16_t* g = (const bf16_t*)A + (size_t)(row0 + row) * KD +
                                  kk + ((colb ^ ((row & 7) << 4)) >> 1);
                gll16(g, (char*)&As[buf][0] + (j * 256 + w * 64) * 16);
            }
        }
    };
    auto bstage = [&](int buf, int kk) {       // pre-swizzled source
        #pragma unroll
        for (int j = 0; j < 2; j++) {
            const int idx = j * 256 + t;
            const int n = idx >> 3, colb = (idx & 7) * 16;
            const bf16_t* g = Bt + (size_t)(col0 + n) * KD +
                              kk + ((colb ^ ((n & 7) << 4)) >> 1);
            gll16(g, (char*)&Bs[buf][0] + (j * 256 + w * 64) * 16);
        }
    };

    constexpr int NB = KD / 64;
    if constexpr (sizeof(AT) == 4) { aload(0); awrite(0); }
    else                            astage_gll(0, 0);
    bstage(0, 0);

    const char* AsC0 = (const char*)&As[0][0];
    const char* BsC0 = (const char*)&Bs[0][0];
    for (int s = 0; s < NB; s++) {
        __syncthreads();                 // buf[s&1] ready (vmcnt+lgkm drain)
        const int cur = s & 1;
        if (s + 1 < NB) {
            bstage(cur ^ 1, (s + 1) * 64);
            if constexpr (sizeof(AT) == 4) aload((s + 1) * 64);
            else                           astage_gll(cur ^ 1, (s + 1) * 64);
        }
        const char* AsC = AsC0 + cur * (64 * 128);
        const char* BsC = BsC0 + cur * (64 * 128);
        #pragma unroll
        for (int h = 0; h < 2; h++) {
            bf16x8 af[2], bfr[2];
            #pragma unroll
            for (int mf = 0; mf < 2; mf++) {
                const int R = wr * 32 + mf * 16 + lrow;
                af[mf] = *(const bf16x8*)(AsC + R * 128 +
                          (((h * 32 + lk8) * 2) ^ ((R & 7) << 4)));
            }
            #pragma unroll
            for (int nf = 0; nf < 2; nf++) {
                const int Rn = wc * 32 + nf * 16 + lrow;
                bfr[nf] = *(const bf16x8*)(BsC + Rn * 128 +
                          (((h * 32 + lk8) * 2) ^ ((Rn & 7) << 4)));
            }
            #pragma unroll
            for (int mf = 0; mf < 2; mf++)
                #pragma unroll
                for (int nf = 0; nf < 2; nf++)
                    acc[mf][nf] = MFMA16(af[mf], bfr[nf], acc[mf][nf]);
        }
        if (s + 1 < NB) { if constexpr (sizeof(AT) == 4) awrite(cur ^ 1); }
    }

    if constexpr (MODE == 2) {
        #pragma unroll
        for (int mf = 0; mf < 2; mf++)
            #pragma unroll
            for (int nf = 0; nf < 2; nf++) {
                const int gcol = col0 + wc * 32 + nf * 16 + lrow;
                const float bv = bias[gcol];
                #pragma unroll
                for (int r = 0; r < 4; r++) {
                    const int grow = row0 + wr * 32 + mf * 16 + lk4 * 4 + r;
                    ((float*)outp)[(size_t)grow * N + gcol] = (acc[mf][nf][r] + bv) * scale;
                }
            }
    } else {
        __syncthreads();   // all MFMA reads of As done before Ct aliasing write
        #pragma unroll
        for (int mf = 0; mf < 2; mf++)
            #pragma unroll
            for (int nf = 0; nf < 2; nf++) {
                const int lcol = wc * 32 + nf * 16 + lrow;
                const float bv = bias[col0 + lcol];
                #pragma unroll
                for (int r = 0; r < 4; r++)
                    Ct[(wr * 32 + mf * 16 + lk4 * 4 + r) * 72 + lcol] =
                        (bf16_t)((acc[mf][nf][r] + bv) * scale);
            }
        __syncthreads();
        const int h = col0 >> 6, b = row0 >> 10;
        bf16_t* op = (bf16_t*)outp + ((size_t)(b * Hn + h) << 16);  // *1024*64
        if constexpr (MODE == 0) {
            #pragma unroll
            for (int j = 0; j < 2; j++) {
                const int sl = j * 32 + (t >> 3), cl0 = (t & 7) * 8;
                bf16x8 v = *(const bf16x8*)&Ct[sl * 72 + cl0];
                *(bf16x8*)&op[(size_t)((row0 & 1023) + sl) * 64 + cl0] = v;
            }
        } else {
            #pragma unroll
            for (int jj = 0; jj < 2; jj++) {
                const int cl = jj * 32 + (t >> 3);
                const int sl0 = (t & 7) * 8;
                bf16x8 v;
                #pragma unroll
                for (int i = 0; i < 8; i++) v[i] = Ct[(sl0 + i) * 72 + cl];
                *(bf16x8*)&op[(size_t)cl * 1024 + (row0 & 1023) + sl0] = v;
            }
        }
    }
}

// ---------------------------------------------------------------------------
// Flash attention, swapped operands, no barriers. XCD-locality swizzle —
// each XCD owns 8 whole heads (bh = xcd + 8*(slot>>4)), so K/V of the heads
// in flight fit its 4MB L2 (was: every head pulled into every XCD, 3x
// overfetch, HBM-latency stalls).
// ---------------------------------------------------------------------------
__global__ __launch_bounds__(256)
void attn_kernel(const bf16_t* __restrict__ kbuf, const bf16_t* __restrict__ vT,
                 const bf16_t* __restrict__ qbuf, const int* __restrict__ qmask,
                 const int* __restrict__ kmask, bf16_t* __restrict__ ctx)
{
    __shared__ bf16_t Pall[4][16 * 64];
    const int t = threadIdx.x, lane = t & 63, w = t >> 6;
    const int bidx = blockIdx.x;
    const int xcd = bidx & 7, slot = bidx >> 3;
    const int qt = slot & 15, bh = xcd + ((slot >> 4) << 3);
    const int b = bh >> 4, h = bh & 15;
    const int lrow = lane & 15, lk4 = lane >> 4, lk8 = lk4 * 8;
    const int wrow0 = qt * 64 + w * 16;
    const bf16_t* kb = kbuf + (size_t)bh * SEQ * Dh;
    const bf16_t* vb = vT + (size_t)bh * Dh * SEQ;
    char* Pw = (char*)&Pall[w][0];
    const int sw = (lrow & 7) << 4;

    bf16x8 aq0, aq1;
    {
        const bf16_t* qp = qbuf + ((size_t)bh * SEQ + wrow0 + lrow) * Dh + lk8;
        aq0 = *(const bf16x8*)(qp);
        aq1 = *(const bf16x8*)(qp + 32);
    }
    const int qm = qmask[b * SEQ + wrow0 + lrow];

    bf16x8 ones;
    #pragma unroll
    for (int i = 0; i < 8; i++) ones[i] = (bf16_t)1.0f;

    float m_run = -__builtin_inff();
    f32x4 o[4] = {};
    f32x4 o_l  = {};     // row-sum accumulator via ones-MFMA

    bf16x8 kc0[4], kc1[4];
    #pragma unroll
    for (int nf = 0; nf < 4; nf++) {
        const bf16_t* kp = kb + (size_t)(nf * 16 + lrow) * Dh + lk8;
        kc0[nf] = *(const bf16x8*)(kp);
        kc1[nf] = *(const bf16x8*)(kp + 32);
    }

    for (int kt = 0; kt < 16; kt++) {
        const int key0 = kt * 64;
        bf16x8 vf0[4], vf1[4];
        #pragma unroll
        for (int nf = 0; nf < 4; nf++) {
            const bf16_t* vp = vb + (size_t)(nf * 16 + lrow) * SEQ + key0 + lk8;
            vf0[nf] = *(const bf16x8*)(vp);
            vf1[nf] = *(const bf16x8*)(vp + 32);
        }
        i32x4 km[4];
        #pragma unroll
        for (int nf = 0; nf < 4; nf++)
            km[nf] = *(const i32x4*)&kmask[b * SEQ + key0 + nf * 16 + lk4 * 4];
        f32x4 s4[4] = {};
        __builtin_amdgcn_s_setprio(1);
        #pragma unroll
        for (int nf = 0; nf < 4; nf++) {
            s4[nf] = MFMA16(kc0[nf], aq0, s4[nf]);
            s4[nf] = MFMA16(kc1[nf], aq1, s4[nf]);
        }
        __builtin_amdgcn_s_setprio(0);
        bf16x8 kn0[4], kn1[4];
        if (kt < 15) {
            #pragma unroll
            for (int nf = 0; nf < 4; nf++) {
                const bf16_t* kp = kb + (size_t)(key0 + 64 + nf * 16 + lrow) * Dh + lk8;
                kn0[nf] = *(const bf16x8*)(kp);
                kn1[nf] = *(const bf16x8*)(kp + 32);
            }
        }
        // mask select (exact -1e18) + tree max
        float p[4][4], mx[4];
        #pragma unroll
        for (int nf = 0; nf < 4; nf++) {
            #pragma unroll
            for (int r = 0; r < 4; r++)
                p[nf][r] = (qm && km[nf][r]) ? s4[nf][r] : -1e18f;
            mx[nf] = fmaxf(fmaxf(p[nf][0], p[nf][1]), fmaxf(p[nf][2], p[nf][3]));
        }
        const float pmax = fmaxf(fmaxf(mx[0], mx[1]), fmaxf(mx[2], mx[3]));
        // defer-max: full path only when a lane's max beats m_run by > 8
        if (!__all(pmax - m_run <= 8.0f)) {
            float mt = fmaxf(pmax, __shfl_xor(pmax, 16));
            mt = fmaxf(mt, __shfl_xor(mt, 32));
            const float resc = __expf(m_run - mt);
            m_run = mt;
            #pragma unroll
            for (int nf = 0; nf < 4; nf++)
                #pragma unroll
                for (int r = 0; r < 4; r++) o[nf][r] *= resc;
            #pragma unroll
            for (int r = 0; r < 4; r++) o_l[r] *= resc;
        }
        #pragma unroll
        for (int nf = 0; nf < 4; nf++)
            #pragma unroll
            for (int r = 0; r < 4; r++) p[nf][r] = __expf(p[nf][r] - m_run);
        // P -> LDS (per-wave strip, swizzled, no barrier)
        #pragma unroll
        for (int nf = 0; nf < 4; nf++) {
            bf16x4 pk;
            #pragma unroll
            for (int r = 0; r < 4; r++) pk[r] = (bf16_t)p[nf][r];
            *(bf16x4*)(Pw + lrow * 128 + ((nf * 32 + lk4 * 8) ^ sw)) = pk;
        }
        bf16x8 pa0 = *(const bf16x8*)(Pw + lrow * 128 + ((lk4 * 16) ^ sw));
        bf16x8 pa1 = *(const bf16x8*)(Pw + lrow * 128 + ((64 + lk4 * 16) ^ sw));
        __builtin_amdgcn_s_setprio(1);
        #pragma unroll
        for (int nf = 0; nf < 4; nf++) {
            o[nf] = MFMA16(vf0[nf], pa0, o[nf]);
            o[nf] = MFMA16(vf1[nf], pa1, o[nf]);
        }
        o_l = MFMA16(ones, pa0, o_l);      // l += sum_k P[k][q]
        o_l = MFMA16(ones, pa1, o_l);
        __builtin_amdgcn_s_setprio(0);
        #pragma unroll
        for (int nf = 0; nf < 4; nf++) { kc0[nf] = kn0[nf]; kc1[nf] = kn1[nf]; }
    }
    // finalize: O/l -> strip [q][d] -> coalesced ctx stores
    const float inv = 1.0f / o_l[0];
    #pragma unroll
    for (int nf = 0; nf < 4; nf++) {
        bf16x4 pk;
        #pragma unroll
        for (int r = 0; r < 4; r++) pk[r] = (bf16_t)(o[nf][r] * inv);
        *(bf16x4*)(Pw + lrow * 128 + ((nf * 32 + lk4 * 8) ^ sw)) = pk;
    }
    const int qp2 = lane >> 2, ch = lane & 3;
    const int sw2 = (qp2 & 7) << 4;
    bf16x8 o0 = *(const bf16x8*)(Pw + qp2 * 128 + ((ch * 32) ^ sw2));
    bf16x8 o1 = *(const bf16x8*)(Pw + qp2 * 128 + ((ch * 32 + 16) ^ sw2));
    bf16_t* cp = ctx + ((size_t)(b * SEQ + wrow0 + qp2)) * 1024 + h * 64 + ch * 16;
    *(bf16x8*)cp = o0;
    *(bf16x8*)(cp + 8) = o1;
}

// ---------------------------------------------------------------------------
// top_score = pre-mask scores of head 0 (coalesced f32 stores).
// Grid 1024: b(2b) x qt(4b) x kq(4b); one 64-key tile per block.
// ---------------------------------------------------------------------------
__global__ __launch_bounds__(256)
void topsc_kernel(const bf16_t* __restrict__ kbuf, const bf16_t* __restrict__ qbuf,
                  float* __restrict__ topsc)
{
    const int t = threadIdx.x, lane = t & 63, w = t >> 6;
    const int bx = blockIdx.x;
    const int b = bx >> 8, qt = (bx >> 4) & 15, kq = bx & 15;
    const int lrow = lane & 15, lk4 = lane >> 4, lk8 = lk4 * 8;
    const int wrow0 = qt * 64 + w * 16;
    const bf16_t* kb = kbuf + ((size_t)(b * Hn)) * SEQ * Dh;   // head 0
    const bf16_t* qp = qbuf + ((size_t)(b * Hn)) * SEQ * Dh
                     + (size_t)(wrow0 + lrow) * Dh + lk8;
    bf16x8 aq0 = *(const bf16x8*)(qp);
    bf16x8 aq1 = *(const bf16x8*)(qp + 32);
    const int key0 = kq * 64;
    f32x4 s4[4] = {};
    #pragma unroll
    for (int nf = 0; nf < 4; nf++) {
        const bf16_t* kp = kb + (size_t)(key0 + nf * 16 + lrow) * Dh + lk8;
        s4[nf] = MFMA16(aq0, *(const bf16x8*)(kp), s4[nf]);
        s4[nf] = MFMA16(aq1, *(const bf16x8*)(kp + 32), s4[nf]);
    }
    #pragma unroll
    for (int nf = 0; nf < 4; nf++)
        #pragma unroll
        for (int r = 0; r < 4; r++)
            topsc[(size_t)(b * SEQ + wrow0 + lk4 * 4 + r) * SEQ +
                  key0 + nf * 16 + lrow] = s4[nf][r];
}

// ---------------------------------------------------------------------------
extern "C" void kernel_launch(void* const* d_in, const int* in_sizes, int n_in,
                              void* d_out, int out_size, void* d_ws, size_t ws_size,
                              hipStream_t stream)
{
    const float* key   = (const float*)d_in[0];
    const float* value = (const float*)d_in[1];
    const float* query = (const float*)d_in[2];
    const int*   mask  = (const int*)d_in[3];
    const int*   amask = (const int*)d_in[4];
    const float* Wk = (const float*)d_in[5];
    const float* bk = (const float*)d_in[6];
    const float* Wv = (const float*)d_in[7];
    const float* bv = (const float*)d_in[8];
    const float* Wq = (const float*)d_in[9];
    const float* bq = (const float*)d_in[10];
    const float* Wo = (const float*)d_in[11];
    const float* bo = (const float*)d_in[12];

    const size_t per = (size_t)Bn * Hn * SEQ * Dh;          // 4M elems
    bf16_t* kproj = (bf16_t*)d_ws;
    bf16_t* vT    = kproj + per;
    bf16_t* qproj = vT + per;
    bf16_t* ctx   = qproj + per;

    float* outf = (float*)d_out;
    bf16_t* WkT = (bf16_t*)(outf + (size_t)Bn * SEQ * 768);
    bf16_t* WvT = WkT + 1024 * 1024;
    bf16_t* WqT = WvT + 1024 * 1024;    // [1024][768]
    bf16_t* WoT = WqT + 1024 * 768;     // [768][1024]
    float* topsc = outf + (size_t)Bn * SEQ * 768;

    wtrans_kernel<<<896, 256, 0, stream>>>(Wk, Wv, Wq, Wo, WkT, WvT, WqT, WoT);
    gemm_bt<1024, 1024, 0, 16, float><<<1024, 256, 0, stream>>>(key,   WkT, bk, kproj, 1.0f);
    gemm_bt<1024, 1024, 1, 16, float><<<1024, 256, 0, stream>>>(value, WvT, bv, vT,    1.0f);
    gemm_bt< 768, 1024, 0, 16, float><<<1024, 256, 0, stream>>>(query, WqT, bq, qproj, 0.125f);
    attn_kernel<<<1024, 256, 0, stream>>>(kproj, vT, qproj, mask, amask, ctx);
    gemm_bt<1024, 768, 2, 12, bf16_t><<<768, 256, 0, stream>>>(ctx, WoT, bo, outf, 1.0f);
    topsc_kernel<<<1024, 256, 0, stream>>>(kproj, qproj, topsc);
}